// Round 6
// baseline (105.895 us; speedup 1.0000x reference)
//
#include <hip/hip_runtime.h>

// CTC batch cost (Keras semantics): blank = C-1, full-length inputs/labels.
// Two-phase:
//   Phase 1 (ctc_gather4): per (b,t,lane) emit float4 {p[l0]+EPS, p[l1]+EPS,
//     p[blank]+EPS, 0} -> cmp[B][T][64] float4. One coalesced dwordx4 per
//     lane per timestep for the scan.
//   Phase 2 (ctc_scan4): scaled linear-domain forward DP, one wave per row.
//     Lane l owns extended states 4l..4l+3 (+phantom 4l+4, real on lane 63).
//     DPP wave_shr:1 for the cross-lane shift (VALU-only). Per-lane
//     power-of-2 rescale every 4 steps (unbounded range; absmax 0.0).
//   R5 lesson: VGPR_Count=48 proved the compiler (targeting occupancy we
//     don't need) sank the prefetch ring loads to their uses -> ~165cyc/step
//     latency-bound. Fix: __launch_bounds__(64,1) to unlock VGPRs + 1 load
//     per step (float4) + DEPTH=32 ring (~800 cyc coverage).

constexpr int   B_DIM = 64;
constexpr int   T_LEN = 1024;
constexpr int   C_DIM = 512;
constexpr int   L_LEN = 128;
constexpr int   BLANK = C_DIM - 1;
constexpr float EPSF  = 1e-7f;
constexpr float LN2F  = 0.69314718055994530942f;

// lane l <- lane l-1, lane 0 <- 0 (DPP wave_shr:1, bound_ctrl=0-fill). VALU-only.
__device__ __forceinline__ float wshr1_f(float x) {
    return __int_as_float(__builtin_amdgcn_update_dpp(
        0, __float_as_int(x), 0x138, 0xf, 0xf, true));
}
__device__ __forceinline__ int wshr1_i(int x) {
    return __builtin_amdgcn_update_dpp(0, x, 0x138, 0xf, 0xf, true);
}

__global__ __launch_bounds__(256)
void ctc_gather4(const int* __restrict__ yt, const float* __restrict__ yh,
                 float4* __restrict__ cmp)
{
    const int id = blockIdx.x * 256 + threadIdx.x;   // over B*T*64
    constexpr int NTOT = B_DIM * T_LEN * 64;
    if (id >= NTOT) return;
    const int lane = id & 63;
    const int bt   = id >> 6;
    const int b    = bt >> 10;                       // T_LEN = 1024
    const int* __restrict__ lb = yt + b * L_LEN;
    const float* __restrict__ row = yh + (size_t)bt * C_DIM;
    float4 v;
    v.x = row[lb[2 * lane]]     + EPSF;              // state 4l+1
    v.y = row[lb[2 * lane + 1]] + EPSF;              // state 4l+3
    v.z = row[BLANK]            + EPSF;              // blank (per-lane copy)
    v.w = 0.0f;
    cmp[id] = v;                                     // coalesced 16B store
}

__global__ __launch_bounds__(64, 1)   // 1 wave/EU min -> full VGPR budget
void ctc_scan4(const int* __restrict__ yt, const float4* __restrict__ cmp,
               float* __restrict__ out)
{
    const int b    = blockIdx.x;
    const int lane = threadIdx.x;
    const int* __restrict__ lb = yt + b * L_LEN;

    const int l0 = lb[2 * lane];                    // state 4l+1
    const int l1 = lb[2 * lane + 1];                // state 4l+3
    const int lp = lane ? lb[2 * lane - 1] : 0;
    const float sk1 = (lane > 0 && l0 != lp && l0 != BLANK) ? 1.0f : 0.0f;
    const float sk3 = (l1 != l0 && l1 != BLANK) ? 1.0f : 0.0f;

    const float4* __restrict__ base = cmp + ((size_t)b * T_LEN) * 64 + lane;

    // "t=-1" init: a0=1 on lane 0 makes step t=0 produce exactly alpha0.
    float a0 = (lane == 0) ? 1.0f : 0.0f;
    float a1 = 0.0f, a2 = 0.0f, a3 = 0.0f, a4 = 0.0f;
    int   E  = 0;                                   // per-lane exponent
    float sSeed = (lane == 0) ? 0.0f : 1.0f;        // 2^(E_prev - E), 0 masks lane 0

    constexpr int DEPTH = 32;                       // 32 dwordx4 in flight
    float4 ring[DEPTH];
#pragma unroll
    for (int i = 0; i < DEPTH; ++i) ring[i] = base[(size_t)i * 64];

#pragma unroll 1
    for (int blk = 0; blk < T_LEN / DEPTH; ++blk) {
#pragma unroll
        for (int q = 0; q < DEPTH / 4; ++q) {
#pragma unroll
            for (int i = 0; i < 4; ++i) {
                const int slot = q * 4 + i;
                const float P1 = ring[slot].x;
                const float P3 = ring[slot].y;
                const float Pb = ring[slot].z;

                int tn = blk * DEPTH + slot + DEPTH;      // prefetch t+DEPTH
                tn = tn < T_LEN ? tn : T_LEN - 1;         // (tail clamped)
                ring[slot] = base[(size_t)tn * 64];

                const float pa3 = wshr1_f(a3) * sSeed;    // alpha[4l-1], rescaled
                const float n0 = Pb * (a0 + pa3);
                const float n1 = P1 * (a1 + a0 + sk1 * pa3);
                const float n2 = Pb * (a2 + a1);
                const float n3 = P3 * (a3 + a2 + sk3 * a1);
                const float n4 = Pb * (a4 + a3);
                a0 = n0; a1 = n1; a2 = n2; a3 = n3; a4 = n4;
            }
            // per-lane rescale every 4 steps (max decay >= (1e-7)^4 = 2^-93)
            const float m = fmaxf(fmaxf(fmaxf(a0, a1), fmaxf(a2, a3)), a4);
            const bool has = m > 0.0f;
            int eb = (int)((__float_as_uint(m) >> 23) & 0xFFu);
            eb = eb < 1 ? 1 : eb;                   // denormal m -> scale up
            if (has) {
                const float scl = __uint_as_float((unsigned)(254 - eb) << 23);
                a0 *= scl; a1 *= scl; a2 *= scl; a3 *= scl; a4 *= scl;
                E += eb - 127;
            }
            int pE = wshr1_i(E);
            if (!has && lane > 0) E = pE;           // empty lane adopts neighbor's E
            pE = wshr1_i(E);
            const int d = pE - E;
            sSeed = (lane == 0 || d < -126)
                  ? 0.0f
                  : __uint_as_float((unsigned)(127 + (d > 126 ? 126 : d)) << 23);
        }
    }

    if (lane == 63)                                 // states 255 (a3) + 256 (a4)
        out[b] = -((log2f(a3 + a4) + (float)E) * LN2F);
}

// Fallback (no workspace): direct 3-gather scan on yh, proven in R1/R2.
__global__ __launch_bounds__(64, 1)
void ctc_scan_direct(const int* __restrict__ yt, const float* __restrict__ src,
                     float* __restrict__ out)
{
    const int b    = blockIdx.x;
    const int lane = threadIdx.x;
    const int* __restrict__ lb = yt + b * L_LEN;

    const int l0 = lb[2 * lane];
    const int l1 = lb[2 * lane + 1];
    const int lp = lane ? lb[2 * lane - 1] : 0;
    const float sk1 = (lane > 0 && l0 != lp && l0 != BLANK) ? 1.0f : 0.0f;
    const float sk3 = (l1 != l0 && l1 != BLANK) ? 1.0f : 0.0f;

    const float* __restrict__ base = src + (size_t)b * T_LEN * C_DIM;

    float a0 = (lane == 0) ? 1.0f : 0.0f;
    float a1 = 0.0f, a2 = 0.0f, a3 = 0.0f, a4 = 0.0f;
    int   E  = 0;
    float sSeed = (lane == 0) ? 0.0f : 1.0f;

    constexpr int DEPTH = 16;
    float pb[DEPTH], p1[DEPTH], p3[DEPTH];
    auto LOADT = [&](int slot, int t) {
        const float* row = base + (size_t)t * C_DIM;
        pb[slot] = row[BLANK]; p1[slot] = row[l0]; p3[slot] = row[l1];
    };
#pragma unroll
    for (int i = 0; i < DEPTH; ++i) LOADT(i, i);

#pragma unroll 1
    for (int blk = 0; blk < T_LEN / DEPTH; ++blk) {
#pragma unroll
        for (int q = 0; q < DEPTH / 4; ++q) {
#pragma unroll
            for (int i = 0; i < 4; ++i) {
                const int slot = q * 4 + i;
                const float Pb = pb[slot] + EPSF;
                const float P1 = p1[slot] + EPSF;
                const float P3 = p3[slot] + EPSF;
                int tn = blk * DEPTH + slot + DEPTH;
                tn = tn < T_LEN ? tn : T_LEN - 1;
                LOADT(slot, tn);
                const float pa3 = wshr1_f(a3) * sSeed;
                const float n0 = Pb * (a0 + pa3);
                const float n1 = P1 * (a1 + a0 + sk1 * pa3);
                const float n2 = Pb * (a2 + a1);
                const float n3 = P3 * (a3 + a2 + sk3 * a1);
                const float n4 = Pb * (a4 + a3);
                a0 = n0; a1 = n1; a2 = n2; a3 = n3; a4 = n4;
            }
            const float m = fmaxf(fmaxf(fmaxf(a0, a1), fmaxf(a2, a3)), a4);
            const bool has = m > 0.0f;
            int eb = (int)((__float_as_uint(m) >> 23) & 0xFFu);
            eb = eb < 1 ? 1 : eb;
            if (has) {
                const float scl = __uint_as_float((unsigned)(254 - eb) << 23);
                a0 *= scl; a1 *= scl; a2 *= scl; a3 *= scl; a4 *= scl;
                E += eb - 127;
            }
            int pE = wshr1_i(E);
            if (!has && lane > 0) E = pE;
            pE = wshr1_i(E);
            const int d = pE - E;
            sSeed = (lane == 0 || d < -126)
                  ? 0.0f
                  : __uint_as_float((unsigned)(127 + (d > 126 ? 126 : d)) << 23);
        }
    }

    if (lane == 63)
        out[b] = -((log2f(a3 + a4) + (float)E) * LN2F);
}

extern "C" void kernel_launch(void* const* d_in, const int* in_sizes, int n_in,
                              void* d_out, int out_size, void* d_ws, size_t ws_size,
                              hipStream_t stream)
{
    const int*   yt  = (const int*)d_in[0];
    const float* yh  = (const float*)d_in[1];
    float*       out = (float*)d_out;

    const size_t need = (size_t)B_DIM * T_LEN * 64 * sizeof(float4);
    if (d_ws != nullptr && ws_size >= need) {
        float4* cmp = (float4*)d_ws;
        constexpr int NTOT = B_DIM * T_LEN * 64;
        ctc_gather4<<<dim3((NTOT + 255) / 256), dim3(256), 0, stream>>>(yt, yh, cmp);
        ctc_scan4<<<dim3(B_DIM), dim3(64), 0, stream>>>(yt, cmp, out);
    } else {
        ctc_scan_direct<<<dim3(B_DIM), dim3(64), 0, stream>>>(yt, yh, out);
    }
}